// Round 15
// baseline (266.893 us; speedup 1.0000x reference)
//
#include <hip/hip_runtime.h>
#include <math.h>

#define EPS 1e-5f

typedef float f32x2 __attribute__((ext_vector_type(2)));
typedef float f32x4 __attribute__((ext_vector_type(4)));
__device__ __forceinline__ f32x2 fma2(f32x2 a, f32x2 b, f32x2 c) {
    return __builtin_elementwise_fma(a, b, c);
}
__device__ __forceinline__ f32x4 fma4(f32x4 a, f32x4 b, f32x4 c) {
    return __builtin_elementwise_fma(a, b, c);
}
__device__ __forceinline__ f32x2 sp2(float x) { f32x2 r = {x, x}; return r; }

// DPP row_shl:N add (VALU pipe, not DS). bound_ctrl=true -> OOB lanes read 0.
// row_shl accumulates downward: full 16-lane row sum lands at lane 0 of the row.
__device__ __forceinline__ float dpp_add_shl(float v, int n) {
    int x;
    switch (n) {
        case 1: x = __builtin_amdgcn_mov_dpp(__float_as_int(v), 0x101, 0xF, 0xF, true); break;
        case 2: x = __builtin_amdgcn_mov_dpp(__float_as_int(v), 0x102, 0xF, 0xF, true); break;
        case 4: x = __builtin_amdgcn_mov_dpp(__float_as_int(v), 0x104, 0xF, 0xF, true); break;
        default: x = __builtin_amdgcn_mov_dpp(__float_as_int(v), 0x108, 0xF, 0xF, true); break;
    }
    return v + __int_as_float(x);
}
// sum over each 16-lane row; result valid at lane (row base + 0)
__device__ __forceinline__ float row_sum16(float v) {
    v = dpp_add_shl(v, 1);
    v = dpp_add_shl(v, 2);
    v = dpp_add_shl(v, 4);
    v = dpp_add_shl(v, 8);
    return v;
}

// ---------------- workspace layout (floats) ----------------
// qkv   : 0          [7,340,032]  qkv, overwritten in-place with "so"
// Pq    : +7340032   [57,344]     partials: qkv [256][224], reused as sim [48][1024]
// prm   : +7397376   [560]        qkvP[256] | simP[48] | outP[256]
// tab   : +7397936   [3,128]      Rq/Rk/Sq/Sk window sums [2240] + rvrev [888]
// sumsO : +7401064   [256]        fallback out stats
// ctrs  : +7401320   [2 ints]     last-block counters (qkv, sim)
// P2    : +7401472   [262,144]    out partials [256][1024]

// =============== K1: tiled GEMM + transpose-write + stats + FUSED qkv-BN finalize;
//                 block 448 computes window-sum tables + reversed rv ===============
__global__ __launch_bounds__(256) void k_qkv2(const float* __restrict__ x,
                                              const float* __restrict__ w,
                                              const float* __restrict__ rel,
                                              float* __restrict__ qkv,
                                              float* __restrict__ P,
                                              float* __restrict__ tab,
                                              const float* __restrict__ gq,
                                              const float* __restrict__ bq,
                                              float* __restrict__ prm,
                                              int* __restrict__ ctr) {
    __shared__ __align__(16) float X[64 * 256];
    __shared__ float T[8 * 264];
    __shared__ int lastf;
    const int t = threadIdx.x;

    if (blockIdx.x == 448) {            // ---- prep path ----
        float* r = X;
        for (int idx = t; idx < 444; idx += 256)
            *(float4*)&r[idx * 4] = *(const float4*)&rel[idx * 4];
        __syncthreads();
        for (int o = t; o < 2240; o += 256) {
            int row = o / 56, i = o - row * 56;
            float s = 0.f;
            if (row < 8) {
                const float* rr = &r[row * 111];
#pragma unroll
                for (int u = 0; u < 56; ++u) s += rr[i + u];
            } else if (row < 24) {
                int p = row - 8;
                const float* ra = &r[(p >> 2) * 111];
                const float* rb = &r[(p & 3) * 111];
#pragma unroll
                for (int u = 0; u < 56; ++u) s = fmaf(ra[i + u], rb[i + u], s);
            } else {
                int p = row - 24;
                const float* ra = &r[(4 + (p >> 2)) * 111];
                const float* rb = &r[(4 + (p & 3)) * 111];
#pragma unroll
                for (int u = 0; u < 56; ++u) s = fmaf(ra[i + u], rb[i + u], s);
            }
            tab[o] = s;
        }
        for (int o = t; o < 888; o += 256) {
            int c = o / 111, u = o - c * 111;
            tab[2240 + o] = rel[888 + c * 111 + 110 - u];
        }
        return;
    }

    const int tile = blockIdx.x % 224;
    const int half = blockIdx.x / 224;
    const int m0 = tile << 8;
    const int s = m0 / 1792;
    const int i0 = (m0 - s * 1792) >> 5;

    const float* xb = x + m0;
#pragma unroll
    for (int j = 0; j < 16; ++j) {
        int f = (j << 8) + t;
        int c = f >> 6, col = (f & 63) << 2;
        *(float4*)&X[(c << 8) + col] = *(const float4*)&xb[(size_t)c * 57344 + col];
    }
    __syncthreads();

    float* qb = qkv + (size_t)s * 229376 + i0;

    for (int oc = half * 8; oc < half * 8 + 8; ++oc) {
        const int o0 = oc << 3;
        const float* wp = w + (o0 << 6);
        f32x2 a01 = {0, 0}, a23 = {0, 0}, a45 = {0, 0}, a67 = {0, 0};
        for (int c = 0; c < 64; ++c) {
            float xv = X[(c << 8) + t];
            f32x2 w01 = {wp[c], wp[64 + c]};
            f32x2 w23 = {wp[128 + c], wp[192 + c]};
            f32x2 w45 = {wp[256 + c], wp[320 + c]};
            f32x2 w67 = {wp[384 + c], wp[448 + c]};
            f32x2 xs = sp2(xv);
            a01 = fma2(w01, xs, a01);
            a23 = fma2(w23, xs, a23);
            a45 = fma2(w45, xs, a45);
            a67 = fma2(w67, xs, a67);
        }
        float accv[8] = {a01.x, a01.y, a23.x, a23.y, a45.x, a45.y, a67.x, a67.y};
        __syncthreads();
#pragma unroll
        for (int k = 0; k < 8; ++k) T[k * 264 + t + (t >> 5)] = accv[k];
        __syncthreads();
#pragma unroll
        for (int e = 0; e < 8; ++e) {
            int flat = (e << 8) + t;
            int wcol = flat >> 6, oo = (flat >> 3) & 7, il = flat & 7;
            int mm = (il << 5) + wcol;
            qb[(size_t)wcol * 7168 + (o0 + oo) * 56 + il] = T[oo * 264 + mm + (mm >> 5)];
        }
        {
            int row = t >> 5, part = t & 31;
            float s1 = 0.f, s2 = 0.f;
#pragma unroll
            for (int e = 0; e < 8; ++e) {
                int mm = (part << 3) + e;
                float v = T[row * 264 + mm + (mm >> 5)];
                s1 += v; s2 += v * v;
            }
            s1 = row_sum16(s1);
            s2 = row_sum16(s2);
            s1 += __shfl_xor(s1, 16);
            s2 += __shfl_xor(s2, 16);
            if (part == 0) {
                P[(o0 + row) * 224 + tile] = s1;
                P[(128 + o0 + row) * 224 + tile] = s2;
            }
        }
    }

    // ---- last-block fused qkv-BN finalize ----
    __threadfence();
    __syncthreads();
    if (t == 0) lastf = (atomicAdd(ctr, 1) == 447);
    __syncthreads();
    if (!lastf) return;
    __threadfence();
    {
        int c = t & 127, which = t >> 7;            // 2 threads per channel
        const float* row = P + (size_t)(which * 128 + c) * 224;
        f32x4 a4 = {0, 0, 0, 0};
#pragma unroll
        for (int p = 0; p < 56; ++p) a4 += *(const f32x4*)&row[p * 4];
        X[t] = (a4.x + a4.y) + (a4.z + a4.w);       // reuse X as scratch
        __syncthreads();
        if (t < 128) {
            float m = X[t] * (1.f / 57344.f);
            float v = X[128 + t] * (1.f / 57344.f) - m * m;
            float sc = gq[t] * rsqrtf(v + EPS);
            prm[t] = sc;
            prm[128 + t] = bq[t] - m * sc;
        }
    }
}

// =============== small finalize (fallback out BN) ===============
__global__ void k_fin(const float* __restrict__ sums, const float* __restrict__ g,
                      const float* __restrict__ bb, float* __restrict__ prm,
                      int nch, float invN) {
    int c = threadIdx.x;
    if (c >= nch) return;
    float m = sums[c] * invN;
    float v = sums[nch + c] * invN - m * m;
    float sc = g[c] * rsqrtf(v + EPS);
    prm[c] = sc;
    prm[nch + c] = bb[c] - m * sc;
}

// =============== K3: algebraic sim statistics + FUSED sim-BN finalize ===============
__global__ __launch_bounds__(256) void k_sim3(const float* __restrict__ qkv,
                                              const float* __restrict__ prmQ,
                                              const float* __restrict__ tab,
                                              float* __restrict__ P,
                                              const float* __restrict__ gs,
                                              const float* __restrict__ bs,
                                              float* __restrict__ prmOut,
                                              int* __restrict__ ctr) {
    __shared__ __align__(16) float qn[64 * 60];
    __shared__ __align__(16) float T[40 * 60];
    __shared__ float red[8 * 6];
    __shared__ float rsf[48];
    __shared__ int lastf;
    const int t = threadIdx.x, b = blockIdx.x;

    const float* span = qkv + (size_t)b * 7168;
    for (int idx = t; idx < 896; idx += 256) {
        int e0 = idx * 4;
        int g = e0 / 448, r = e0 - g * 448, c = r / 56, i = r - c * 56;
        int ch = g * 16 + c;
        float sc = prmQ[ch], sh = prmQ[128 + ch];
        float4 vv = *(const float4*)&span[g * 896 + r];
        float4 o;
        o.x = vv.x * sc + sh; o.y = vv.y * sc + sh;
        o.z = vv.z * sc + sh; o.w = vv.w * sc + sh;
        *(float4*)&qn[(g * 8 + c) * 60 + i] = o;
    }
    for (int idx = t; idx < 560; idx += 256) {
        int e0 = idx * 4;
        int row = e0 / 56, i = e0 - row * 56;
        int lr = (row < 8) ? (32 + row) : (row - 8);
        *(float4*)&T[lr * 60 + i] = *(const float4*)&tab[e0];
    }
    __syncthreads();

    const int g = t >> 5, u = t & 31;
    const int half = (u < 16) ? 0 : 4;
    const float* rowA = &qn[g * 480 + (half + ((u >> 2) & 3)) * 60];
    const float* rowB = &qn[g * 480 + (half + (u & 3)) * 60];
    const float* tabS = &T[u * 60];
    const float* tabR = &T[(32 + half + (u & 3)) * 60];

    f32x4 gram4 = {0, 0, 0, 0}, wgt4 = {0, 0, 0, 0};
    f32x4 lin14 = {0, 0, 0, 0}, lin24 = {0, 0, 0, 0};
#pragma unroll
    for (int i = 0; i < 56; i += 4) {
        f32x4 a = *(const f32x4*)&rowA[i];
        f32x4 b2 = *(const f32x4*)&rowB[i];
        f32x4 p = a * b2;
        gram4 += p;
        wgt4 = fma4(p, *(const f32x4*)&tabS[i], wgt4);
        lin14 += b2;
        lin24 = fma4(b2, *(const f32x4*)&tabR[i], lin24);
    }
    float gram = (gram4.x + gram4.y) + (gram4.z + gram4.w);
    float wgt = (wgt4.x + wgt4.y) + (wgt4.z + wgt4.w);
    float lin1 = (lin14.x + lin14.y) + (lin14.z + lin14.w);
    float lin2 = (lin24.x + lin24.y) + (lin24.z + lin24.w);

    float linP = __shfl_xor(lin1, 16);
    float gramP = __shfl_xor(gram, 16);
    float v0 = (u < 4) ? lin1 * linP : 0.f;
    float v1 = (u < 16) ? gram * gramP : 0.f;
    float v2 = (u < 4) ? lin2 : 0.f;
    float v3 = (u < 16) ? wgt : 0.f;
    float v4 = (u >= 16 && u < 20) ? lin2 : 0.f;
    float v5 = (u >= 16) ? wgt : 0.f;
    v0 = row_sum16(v0); v1 = row_sum16(v1); v2 = row_sum16(v2);
    v3 = row_sum16(v3); v4 = row_sum16(v4); v5 = row_sum16(v5);
    v0 += __shfl_xor(v0, 16); v1 += __shfl_xor(v1, 16);
    v2 += __shfl_xor(v2, 16); v3 += __shfl_xor(v3, 16);
    v4 += __shfl_xor(v4, 16); v5 += __shfl_xor(v5, 16);
    if (u == 0) {
        red[g * 6 + 0] = v0; red[g * 6 + 1] = v1; red[g * 6 + 2] = v2;
        red[g * 6 + 3] = v3; red[g * 6 + 4] = v4; red[g * 6 + 5] = v5;
    }
    __syncthreads();
    if (t < 48) {
        int g2 = t / 6, s = t - g2 * 6;
        int row = ((s & 1) ? 24 : 0) + (s >> 1) * 8 + g2;
        P[(size_t)row * 1024 + b] = red[g2 * 6 + s];
    }

    // ---- last-block fused sim-BN finalize ----
    __threadfence();
    __syncthreads();
    if (t == 0) lastf = (atomicAdd(ctr, 1) == 1023);
    __syncthreads();
    if (!lastf) return;
    __threadfence();
    {
        float s = 0.f;
        if (t < 192) {
            int row = t >> 2, q = t & 3;             // 4 threads per row
            const float* rp = P + (size_t)row * 1024 + q * 256;
            f32x4 a4 = {0, 0, 0, 0};
#pragma unroll
            for (int p = 0; p < 64; ++p) a4 += *(const f32x4*)&rp[p * 4];
            s = (a4.x + a4.y) + (a4.z + a4.w);
        }
        s = dpp_add_shl(s, 1);
        s = dpp_add_shl(s, 2);                       // 4-group sum at (t&3)==0
        if (t < 192 && (t & 3) == 0) rsf[t >> 2] = s;
        __syncthreads();
        if (t < 24) {
            float m = rsf[t] * (1.f / 3211264.f);
            float v = rsf[24 + t] * (1.f / 3211264.f) - m * m;
            float sc = gs[t] * rsqrtf(v + EPS);
            prmOut[t] = sc;
            prmOut[24 + t] = bs[t] - m * sc;
        }
    }
}

// =============== K5: fused QK/BN/exp2 -> dual-channel PV, Pm in bf16,
//                 DPP stats, shift-free softmax ===============
__global__ __launch_bounds__(256) void k_main8(float* __restrict__ qkv,
                                               const float* __restrict__ rel,
                                               const float* __restrict__ tabrv,
                                               const float* __restrict__ prmQ,
                                               const float* __restrict__ prmS,
                                               float* __restrict__ P2,
                                               int useP2) {
    const int bg = blockIdx.x;
    const int g = bg & 7;
    __shared__ __align__(16) float S[16 * 60];       // q 0-3, k 4-7, v 8-15
    __shared__ __align__(16) float rall[1776];       // rq[4][111] rk[4][111] rvrev[8][111]
    __shared__ __align__(16) unsigned short Pms[56 * 72];  // bf16 exp values
    __shared__ float red[128];

    const int t = threadIdx.x;
    float* span = qkv + (size_t)bg * 896;

    if (t < 224) {
        int e0 = t * 4;
        int c = e0 / 56, i = e0 - c * 56;
        int ch = g * 16 + c;
        float sc = prmQ[ch], sh = prmQ[128 + ch];
        float4 vv = *(const float4*)&span[e0];
        float4 o;
        o.x = vv.x * sc + sh; o.y = vv.y * sc + sh;
        o.z = vv.z * sc + sh; o.w = vv.w * sc + sh;
        *(float4*)&S[c * 60 + i] = o;
    }
    for (int idx = t; idx < 222; idx += 256)
        *(float4*)&rall[idx * 4] = *(const float4*)&rel[idx * 4];
    for (int idx = t; idx < 222; idx += 256)
        *(float4*)&rall[888 + idx * 4] = *(const float4*)&tabrv[idx * 4];
    __syncthreads();

    const int lane = t & 63, w = t >> 6;
    const int i_base = w * 14;
    const bool act = lane < 56;
    const int j = act ? lane : 0;

    const float k0 = S[240 + j], k1 = S[300 + j], k2 = S[360 + j], k3 = S[420 + j];
    const float LOG2E = 1.4426950408889634f;
    const float sc_qk = prmS[g] * LOG2E, sc_qr = prmS[8 + g] * LOG2E, sc_kr = prmS[16 + g] * LOG2E;

#pragma unroll 2
    for (int r = 0; r < 14; r += 2) {
        const int i0 = i_base + r;
        f32x2 q0 = *(const f32x2*)&S[i0];
        f32x2 q1 = *(const f32x2*)&S[60 + i0];
        f32x2 q2 = *(const f32x2*)&S[120 + i0];
        f32x2 q3 = *(const f32x2*)&S[180 + i0];
        const float* rq = &rall[i0 - j + 55];
        const float* rk = &rall[444 + j - i0 + 54];

        f32x2 qk = q0 * k0;
        qk = fma2(q1, sp2(k1), qk);
        qk = fma2(q2, sp2(k2), qk);
        qk = fma2(q3, sp2(k3), qk);

        f32x2 rq0 = {rq[0], rq[1]},     rq1 = {rq[111], rq[112]};
        f32x2 rq2 = {rq[222], rq[223]}, rq3 = {rq[333], rq[334]};
        f32x2 qr = q0 * rq0;
        qr = fma2(q1, rq1, qr);
        qr = fma2(q2, rq2, qr);
        qr = fma2(q3, rq3, qr);

        f32x2 rk0 = {rk[1], rk[0]},     rk1 = {rk[112], rk[111]};
        f32x2 rk2 = {rk[223], rk[222]}, rk3 = {rk[334], rk[333]};
        f32x2 kr = sp2(k0) * rk0;
        kr = fma2(sp2(k1), rk1, kr);
        kr = fma2(sp2(k2), rk2, kr);
        kr = fma2(sp2(k3), rk3, kr);

        f32x2 s = qk * sc_qk;
        s = fma2(qr, sp2(sc_qr), s);
        s = fma2(kr, sp2(sc_kr), s);
        float e0 = __builtin_amdgcn_exp2f(s.x);
        float e1 = __builtin_amdgcn_exp2f(s.y);
        if (act) {
            unsigned int b0 = __float_as_uint(e0);
            unsigned int b1 = __float_as_uint(e1);
            Pms[i0 * 72 + j] = (unsigned short)((b0 + 0x8000u) >> 16);
            Pms[(i0 + 1) * 72 + j] = (unsigned short)((b1 + 0x8000u) >> 16);
        }
    }
    // no __syncthreads: each wave consumes only its own rows (DS pipe in-order)

    const int il = lane & 15, cc = lane >> 4;
    const bool pact = il < 14;
    const int i = pact ? (i_base + il) : i_base;
    const int cA = cc, cB = cc + 4;

    const unsigned short* Pb = &Pms[i * 72];
    const float* vbA = &S[(8 + cA) * 60];
    const float* vbB = &S[(8 + cB) * 60];
    const float* rvA = &rall[888 + cA * 111 + 55 - i];
    const float* rvB = &rall[888 + cB * 111 + 55 - i];
    f32x4 svA = {0, 0, 0, 0}, sveA = {0, 0, 0, 0};
    f32x4 svB = {0, 0, 0, 0}, sveB = {0, 0, 0, 0};
    f32x4 rs4 = {0, 0, 0, 0};
    for (int jj = 0; jj < 56; jj += 8) {
        uint4 pu = *(const uint4*)&Pb[jj];
        f32x4 pa = {__uint_as_float(pu.x << 16), __uint_as_float(pu.x & 0xFFFF0000u),
                    __uint_as_float(pu.y << 16), __uint_as_float(pu.y & 0xFFFF0000u)};
        f32x4 pb = {__uint_as_float(pu.z << 16), __uint_as_float(pu.z & 0xFFFF0000u),
                    __uint_as_float(pu.w << 16), __uint_as_float(pu.w & 0xFFFF0000u)};
        f32x4 vA0 = *(const f32x4*)&vbA[jj],   vA1 = *(const f32x4*)&vbA[jj + 4];
        f32x4 vB0 = *(const f32x4*)&vbB[jj],   vB1 = *(const f32x4*)&vbB[jj + 4];
        f32x4 rA0 = {rvA[jj], rvA[jj + 1], rvA[jj + 2], rvA[jj + 3]};
        f32x4 rA1 = {rvA[jj + 4], rvA[jj + 5], rvA[jj + 6], rvA[jj + 7]};
        f32x4 rB0 = {rvB[jj], rvB[jj + 1], rvB[jj + 2], rvB[jj + 3]};
        f32x4 rB1 = {rvB[jj + 4], rvB[jj + 5], rvB[jj + 6], rvB[jj + 7]};
        svA = fma4(pa, vA0, svA);   svA = fma4(pb, vA1, svA);
        sveA = fma4(pa, rA0, sveA); sveA = fma4(pb, rA1, sveA);
        svB = fma4(pa, vB0, svB);   svB = fma4(pb, vB1, svB);
        sveB = fma4(pa, rB0, sveB); sveB = fma4(pb, rB1, sveB);
        rs4 += pa; rs4 += pb;
    }
    float rs = (rs4.x + rs4.y) + (rs4.z + rs4.w);
    float inv = __builtin_amdgcn_rcpf(rs);
    float sva = ((svA.x + svA.y) + (svA.z + svA.w)) * inv;
    float svea = ((sveA.x + sveA.y) + (sveA.z + sveA.w)) * inv;
    float svb = ((svB.x + svB.y) + (svB.z + svB.w)) * inv;
    float sveb = ((sveB.x + sveB.y) + (sveB.z + sveB.w)) * inv;
    if (pact) {
        span[(cA * 2) * 56 + i] = sva;
        span[(cA * 2 + 1) * 56 + i] = svea;
        span[(cB * 2) * 56 + i] = svb;
        span[(cB * 2 + 1) * 56 + i] = sveb;
    }
    float a0 = pact ? sva : 0.f,  a1 = pact ? sva * sva : 0.f;
    float a2 = pact ? svea : 0.f, a3 = pact ? svea * svea : 0.f;
    float a4 = pact ? svb : 0.f,  a5 = pact ? svb * svb : 0.f;
    float a6 = pact ? sveb : 0.f, a7 = pact ? sveb * sveb : 0.f;
    a0 = row_sum16(a0); a1 = row_sum16(a1); a2 = row_sum16(a2); a3 = row_sum16(a3);
    a4 = row_sum16(a4); a5 = row_sum16(a5); a6 = row_sum16(a6); a7 = row_sum16(a7);
    if (il == 0) {
        int baseA = cc * 16 + w;
        int baseB = (4 + cc) * 16 + w;
        red[baseA + 0]  = a0;  red[baseA + 4]  = a1;
        red[baseA + 8]  = a2;  red[baseA + 12] = a3;
        red[baseB + 0]  = a4;  red[baseB + 4]  = a5;
        red[baseB + 8]  = a6;  red[baseB + 12] = a7;
    }
    __syncthreads();
    if (useP2 && t < 32) {
        float s = red[t * 4] + red[t * 4 + 1] + red[t * 4 + 2] + red[t * 4 + 3];
        int pass = t >> 4, cc2 = (t >> 2) & 3, v = t & 3;
        int c = cc2 + (pass << 2);
        int ch = g * 16 + c * 2 + (v >> 1);
        int row = (v & 1) ? (128 + ch) : ch;
        P2[(size_t)row * 1024 + (bg >> 3)] = s;
    }
}

// =============== fallback out stats ===============
__global__ __launch_bounds__(256) void k_stats(const float* __restrict__ so,
                                               float* __restrict__ sums) {
    const int t = threadIdx.x;
    const int o = blockIdx.x >> 3;
    const int b0 = (blockIdx.x & 7) << 7;
    float s1 = 0.f, s2 = 0.f;
#pragma unroll
    for (int j = 0; j < 7; ++j) {
        int f = (j << 8) + t;
        int row = f / 14, q = f - row * 14;
        const float* src = so + ((size_t)(b0 + row) * 128 + o) * 56 + (q << 2);
        float4 v = *(const float4*)src;
        s1 += v.x + v.y + v.z + v.w;
        s2 += v.x * v.x + v.y * v.y + v.z * v.z + v.w * v.w;
    }
#pragma unroll
    for (int off = 32; off > 0; off >>= 1) { s1 += __shfl_xor(s1, off); s2 += __shfl_xor(s2, off); }
    if ((t & 63) == 0) { atomicAdd(&sums[o], s1); atomicAdd(&sums[128 + o], s2); }
}

// =============== K7: out BN (derived per-block from P2) + pair-sum + transpose ===============
__global__ __launch_bounds__(256) void k_out3(const float* __restrict__ so,
                                              const float* __restrict__ P2,
                                              const float* __restrict__ prmO,
                                              const float* __restrict__ gO,
                                              const float* __restrict__ bO,
                                              float* __restrict__ out,
                                              int useP2) {
    __shared__ float L[128 * 61];
    __shared__ float rsum[8];
    __shared__ float pr[8];                    // sc[4], sh[4] for channels o0..o0+3
    const int t = threadIdx.x;
    const int s = blockIdx.x & 31;
    const int pc = blockIdx.x >> 5;
    const int o0 = pc << 2;
    const int p0 = pc << 1;

    if (useP2) {
        // each block derives its own 4 channels' BN params from P2 [256][1024]
        int rr = t >> 5, l32 = t & 31;         // 8 rows x 32 threads
        int ch = o0 + (rr & 3);
        int prow = (rr < 4) ? ch : (128 + ch);
        const float* rp = P2 + (size_t)prow * 1024 + l32 * 32;
        f32x4 a4 = {0, 0, 0, 0};
#pragma unroll
        for (int p = 0; p < 8; ++p) a4 += *(const f32x4*)&rp[p * 4];
        float sv = (a4.x + a4.y) + (a4.z + a4.w);
        sv = row_sum16(sv);
        sv += __shfl_xor(sv, 16);
        if (l32 == 0) rsum[rr] = sv;
        __syncthreads();
        if (t < 4) {
            float m = rsum[t] * (1.f / 57344.f);
            float v = rsum[4 + t] * (1.f / 57344.f) - m * m;
            float sc = gO[o0 + t] * rsqrtf(v + EPS);
            pr[t] = sc;
            pr[4 + t] = bO[o0 + t] - m * sc;
        }
    } else {
        if (t < 4) {
            pr[t] = prmO[o0 + t];
            pr[4 + t] = prmO[128 + o0 + t];
        }
    }
    __syncthreads();

#pragma unroll
    for (int j = 0; j < 7; ++j) {
        int f = (j << 8) + t;
        int row = f / 14, q = f - row * 14;
        int ch = row >> 5, wcol = row & 31;
        const float* src = so + ((size_t)(s * 32 + wcol) * 128 + o0 + ch) * 56 + (q << 2);
        float4 v = *(const float4*)src;
        float* dst = &L[row * 61 + (q << 2)];
        dst[0] = v.x; dst[1] = v.y; dst[2] = v.z; dst[3] = v.w;
    }
    __syncthreads();
#pragma unroll
    for (int j = 0; j < 14; ++j) {
        int flat = (j << 8) + t;
        int wcol = flat & 31, r = flat >> 5;
        int i = r % 56, pp = r / 56;
        float v0 = L[((pp * 2) * 32 + wcol) * 61 + i];
        float v1 = L[((pp * 2 + 1) * 32 + wcol) * 61 + i];
        float sc0 = pr[(pp << 1)],     sh0 = pr[4 + (pp << 1)];
        float sc1 = pr[(pp << 1) + 1], sh1 = pr[4 + (pp << 1) + 1];
        out[(((size_t)(p0 + pp) * 32 + s) * 56 + i) * 32 + wcol] =
            v0 * sc0 + sh0 + v1 * sc1 + sh1;
    }
}

extern "C" void kernel_launch(void* const* d_in, const int* in_sizes, int n_in,
                              void* d_out, int out_size, void* d_ws, size_t ws_size,
                              hipStream_t stream) {
    const float* x     = (const float*)d_in[0];
    const float* w_qkv = (const float*)d_in[1];
    const float* g_qkv = (const float*)d_in[2];
    const float* b_qkv = (const float*)d_in[3];
    const float* g_sim = (const float*)d_in[4];
    const float* b_sim = (const float*)d_in[5];
    const float* g_out = (const float*)d_in[6];
    const float* b_out = (const float*)d_in[7];
    const float* rel   = (const float*)d_in[8];
    float* out = (float*)d_out;

    float* ws    = (float*)d_ws;
    float* qkv   = ws;
    float* Pq    = ws + 7340032;
    float* prm   = ws + 7397376;
    float* tab   = ws + 7397936;
    float* sumsO = ws + 7401064;
    int*   ctrs  = (int*)(ws + 7401320);
    float* P2    = ws + 7401472;
    const bool big = ws_size >= (size_t)(7401472 + 262144) * sizeof(float);

    // zero fallback sums + counters (258 floats covers sumsO[256] + 2 ints)
    hipMemsetAsync(sumsO, 0, 258 * sizeof(float), stream);

    k_qkv2<<<449, 256, 0, stream>>>(x, w_qkv, rel, qkv, Pq, tab,
                                    g_qkv, b_qkv, prm, ctrs);
    k_sim3<<<1024, 256, 0, stream>>>(qkv, prm, tab, Pq,
                                     g_sim, b_sim, prm + 256, ctrs + 1);

    if (big) {
        k_main8<<<8192, 256, 0, stream>>>(qkv, rel, tab + 2240, prm, prm + 256, P2, 1);
        k_out3<<<1024, 256, 0, stream>>>(qkv, P2, prm + 304, g_out, b_out, out, 1);
    } else {
        k_main8<<<8192, 256, 0, stream>>>(qkv, rel, tab + 2240, prm, prm + 256, sumsO, 0);
        k_stats<<<1024, 256, 0, stream>>>(qkv, sumsO);
        k_fin<<<1, 128, 0, stream>>>(sumsO, g_out, b_out, prm + 304, 128, 1.f / 57344.f);
        k_out3<<<1024, 256, 0, stream>>>(qkv, P2, prm + 304, g_out, b_out, out, 0);
    }
}

// Round 16
// 112.484 us; speedup vs baseline: 2.3727x; 2.3727x over previous
//
#include <hip/hip_runtime.h>
#include <math.h>

#define EPS 1e-5f

typedef float f32x2 __attribute__((ext_vector_type(2)));
typedef float f32x4 __attribute__((ext_vector_type(4)));
__device__ __forceinline__ f32x2 fma2(f32x2 a, f32x2 b, f32x2 c) {
    return __builtin_elementwise_fma(a, b, c);
}
__device__ __forceinline__ f32x4 fma4(f32x4 a, f32x4 b, f32x4 c) {
    return __builtin_elementwise_fma(a, b, c);
}
__device__ __forceinline__ f32x2 sp2(float x) { f32x2 r = {x, x}; return r; }

// DPP row_shl:N add (VALU pipe, not DS). bound_ctrl=true -> OOB lanes read 0.
// row_shl accumulates downward: full 16-lane row sum lands at lane 0 of the row.
__device__ __forceinline__ float dpp_add_shl(float v, int n) {
    int x;
    switch (n) {
        case 1: x = __builtin_amdgcn_mov_dpp(__float_as_int(v), 0x101, 0xF, 0xF, true); break;
        case 2: x = __builtin_amdgcn_mov_dpp(__float_as_int(v), 0x102, 0xF, 0xF, true); break;
        case 4: x = __builtin_amdgcn_mov_dpp(__float_as_int(v), 0x104, 0xF, 0xF, true); break;
        default: x = __builtin_amdgcn_mov_dpp(__float_as_int(v), 0x108, 0xF, 0xF, true); break;
    }
    return v + __int_as_float(x);
}
// sum over each 16-lane row; result valid at lane (row base + 0)
__device__ __forceinline__ float row_sum16(float v) {
    v = dpp_add_shl(v, 1);
    v = dpp_add_shl(v, 2);
    v = dpp_add_shl(v, 4);
    v = dpp_add_shl(v, 8);
    return v;
}

// ---------------- workspace layout (floats) ----------------
// qkv   : 0          [7,340,032]  qkv, overwritten in-place with "so"
// Pq    : +7340032   [57,344]     partials: qkv [256][224], reused as sim [48][1024]
// prm   : +7397376   [560]        qkvP[256] | simP[48] | outP[256]
// tab   : +7397936   [3,128]      Rq/Rk/Sq/Sk window sums [2240] + rvrev [888]
// sumsO : +7401064   [256]        fallback out stats
// P2    : +7401472   [262,144]    out partials [256][1024]
// NOTE: __threadfence is NOT used anywhere — device-scope fences force per-XCD
// L2 writebacks on MI355X (8 XCDs) and cost ~100 µs/kernel at high block counts
// (measured round 15). Cross-kernel visibility via stream order only.

// =============== K1: tiled GEMM (packed fp32) + transpose-write + stats;
//                 block 448 computes window-sum tables + reversed rv ===============
__global__ __launch_bounds__(256) void k_qkv2(const float* __restrict__ x,
                                              const float* __restrict__ w,
                                              const float* __restrict__ rel,
                                              float* __restrict__ qkv,
                                              float* __restrict__ P,
                                              float* __restrict__ tab) {
    __shared__ __align__(16) float X[64 * 256];
    __shared__ float T[8 * 264];
    const int t = threadIdx.x;

    if (blockIdx.x == 448) {            // ---- prep path ----
        float* r = X;
        for (int idx = t; idx < 444; idx += 256)
            *(float4*)&r[idx * 4] = *(const float4*)&rel[idx * 4];
        __syncthreads();
        for (int o = t; o < 2240; o += 256) {
            int row = o / 56, i = o - row * 56;
            float s = 0.f;
            if (row < 8) {
                const float* rr = &r[row * 111];
#pragma unroll
                for (int u = 0; u < 56; ++u) s += rr[i + u];
            } else if (row < 24) {
                int p = row - 8;
                const float* ra = &r[(p >> 2) * 111];
                const float* rb = &r[(p & 3) * 111];
#pragma unroll
                for (int u = 0; u < 56; ++u) s = fmaf(ra[i + u], rb[i + u], s);
            } else {
                int p = row - 24;
                const float* ra = &r[(4 + (p >> 2)) * 111];
                const float* rb = &r[(4 + (p & 3)) * 111];
#pragma unroll
                for (int u = 0; u < 56; ++u) s = fmaf(ra[i + u], rb[i + u], s);
            }
            tab[o] = s;
        }
        // reversed v-embedding rows so k_main can stage with f32x4
        for (int o = t; o < 888; o += 256) {
            int c = o / 111, u = o - c * 111;
            tab[2240 + o] = rel[888 + c * 111 + 110 - u];
        }
        return;
    }

    const int tile = blockIdx.x % 224;
    const int half = blockIdx.x / 224;
    const int m0 = tile << 8;
    const int s = m0 / 1792;
    const int i0 = (m0 - s * 1792) >> 5;

    const float* xb = x + m0;
#pragma unroll
    for (int j = 0; j < 16; ++j) {
        int f = (j << 8) + t;
        int c = f >> 6, col = (f & 63) << 2;
        *(float4*)&X[(c << 8) + col] = *(const float4*)&xb[(size_t)c * 57344 + col];
    }
    __syncthreads();

    float* qb = qkv + (size_t)s * 229376 + i0;

    for (int oc = half * 8; oc < half * 8 + 8; ++oc) {
        const int o0 = oc << 3;
        const float* wp = w + (o0 << 6);
        f32x2 a01 = {0, 0}, a23 = {0, 0}, a45 = {0, 0}, a67 = {0, 0};
        for (int c = 0; c < 64; ++c) {
            float xv = X[(c << 8) + t];
            f32x2 w01 = {wp[c], wp[64 + c]};
            f32x2 w23 = {wp[128 + c], wp[192 + c]};
            f32x2 w45 = {wp[256 + c], wp[320 + c]};
            f32x2 w67 = {wp[384 + c], wp[448 + c]};
            f32x2 xs = sp2(xv);
            a01 = fma2(w01, xs, a01);
            a23 = fma2(w23, xs, a23);
            a45 = fma2(w45, xs, a45);
            a67 = fma2(w67, xs, a67);
        }
        float accv[8] = {a01.x, a01.y, a23.x, a23.y, a45.x, a45.y, a67.x, a67.y};
        __syncthreads();
#pragma unroll
        for (int k = 0; k < 8; ++k) T[k * 264 + t + (t >> 5)] = accv[k];
        __syncthreads();
#pragma unroll
        for (int e = 0; e < 8; ++e) {
            int flat = (e << 8) + t;
            int wcol = flat >> 6, oo = (flat >> 3) & 7, il = flat & 7;
            int mm = (il << 5) + wcol;
            qb[(size_t)wcol * 7168 + (o0 + oo) * 56 + il] = T[oo * 264 + mm + (mm >> 5)];
        }
        {
            int row = t >> 5, part = t & 31;
            float s1 = 0.f, s2 = 0.f;
#pragma unroll
            for (int e = 0; e < 8; ++e) {
                int mm = (part << 3) + e;
                float v = T[row * 264 + mm + (mm >> 5)];
                s1 += v; s2 += v * v;
            }
            s1 = row_sum16(s1);
            s2 = row_sum16(s2);
            s1 += __shfl_xor(s1, 16);
            s2 += __shfl_xor(s2, 16);
            if (part == 0) {
                P[(o0 + row) * 224 + tile] = s1;
                P[(128 + o0 + row) * 224 + tile] = s2;
            }
        }
    }
}

// =============== coalesced partial reduction -> BN params ===============
__global__ __launch_bounds__(256) void k_fin_red(const float* __restrict__ P,
                                                 const float* __restrict__ g,
                                                 const float* __restrict__ bb,
                                                 float* __restrict__ prm,
                                                 int nch, int npart, float invN) {
    __shared__ float rd[8];
    const int c = blockIdx.x, t = threadIdx.x;
    const float* r1 = P + (size_t)c * npart;
    const float* r2 = P + (size_t)(nch + c) * npart;
    float s1 = 0.f, s2 = 0.f;
    for (int p = t; p < npart; p += 256) { s1 += r1[p]; s2 += r2[p]; }
#pragma unroll
    for (int off = 32; off > 0; off >>= 1) { s1 += __shfl_xor(s1, off); s2 += __shfl_xor(s2, off); }
    if ((t & 63) == 0) { rd[t >> 6] = s1; rd[4 + (t >> 6)] = s2; }
    __syncthreads();
    if (t == 0) {
        s1 = rd[0] + rd[1] + rd[2] + rd[3];
        s2 = rd[4] + rd[5] + rd[6] + rd[7];
        float m = s1 * invN;
        float v = s2 * invN - m * m;
        float sc = g[c] * rsqrtf(v + EPS);
        prm[c] = sc;
        prm[nch + c] = bb[c] - m * sc;
    }
}

// =============== small finalize (fallback out BN) ===============
__global__ void k_fin(const float* __restrict__ sums, const float* __restrict__ g,
                      const float* __restrict__ bb, float* __restrict__ prm,
                      int nch, float invN) {
    int c = threadIdx.x;
    if (c >= nch) return;
    float m = sums[c] * invN;
    float v = sums[nch + c] * invN - m * m;
    float sc = g[c] * rsqrtf(v + EPS);
    prm[c] = sc;
    prm[nch + c] = bb[c] - m * sc;
}

// =============== K3: algebraic sim statistics (f32x4, stride 60) ===============
__global__ __launch_bounds__(256) void k_sim3(const float* __restrict__ qkv,
                                              const float* __restrict__ prmQ,
                                              const float* __restrict__ tab,
                                              float* __restrict__ P) {
    __shared__ __align__(16) float qn[64 * 60];
    __shared__ __align__(16) float T[40 * 60];
    __shared__ float red[8 * 6];
    const int t = threadIdx.x, b = blockIdx.x;

    const float* span = qkv + (size_t)b * 7168;
    for (int idx = t; idx < 896; idx += 256) {
        int e0 = idx * 4;
        int g = e0 / 448, r = e0 - g * 448, c = r / 56, i = r - c * 56;
        int ch = g * 16 + c;
        float sc = prmQ[ch], sh = prmQ[128 + ch];
        float4 vv = *(const float4*)&span[g * 896 + r];
        float4 o;
        o.x = vv.x * sc + sh; o.y = vv.y * sc + sh;
        o.z = vv.z * sc + sh; o.w = vv.w * sc + sh;
        *(float4*)&qn[(g * 8 + c) * 60 + i] = o;
    }
    for (int idx = t; idx < 560; idx += 256) {
        int e0 = idx * 4;
        int row = e0 / 56, i = e0 - row * 56;
        int lr = (row < 8) ? (32 + row) : (row - 8);
        *(float4*)&T[lr * 60 + i] = *(const float4*)&tab[e0];
    }
    __syncthreads();

    const int g = t >> 5, u = t & 31;
    const int half = (u < 16) ? 0 : 4;
    const float* rowA = &qn[g * 480 + (half + ((u >> 2) & 3)) * 60];
    const float* rowB = &qn[g * 480 + (half + (u & 3)) * 60];
    const float* tabS = &T[u * 60];
    const float* tabR = &T[(32 + half + (u & 3)) * 60];

    f32x4 gram4 = {0, 0, 0, 0}, wgt4 = {0, 0, 0, 0};
    f32x4 lin14 = {0, 0, 0, 0}, lin24 = {0, 0, 0, 0};
#pragma unroll
    for (int i = 0; i < 56; i += 4) {
        f32x4 a = *(const f32x4*)&rowA[i];
        f32x4 b2 = *(const f32x4*)&rowB[i];
        f32x4 p = a * b2;
        gram4 += p;
        wgt4 = fma4(p, *(const f32x4*)&tabS[i], wgt4);
        lin14 += b2;
        lin24 = fma4(b2, *(const f32x4*)&tabR[i], lin24);
    }
    float gram = (gram4.x + gram4.y) + (gram4.z + gram4.w);
    float wgt = (wgt4.x + wgt4.y) + (wgt4.z + wgt4.w);
    float lin1 = (lin14.x + lin14.y) + (lin14.z + lin14.w);
    float lin2 = (lin24.x + lin24.y) + (lin24.z + lin24.w);

    float linP = __shfl_xor(lin1, 16);
    float gramP = __shfl_xor(gram, 16);
    float v0 = (u < 4) ? lin1 * linP : 0.f;
    float v1 = (u < 16) ? gram * gramP : 0.f;
    float v2 = (u < 4) ? lin2 : 0.f;
    float v3 = (u < 16) ? wgt : 0.f;
    float v4 = (u >= 16 && u < 20) ? lin2 : 0.f;
    float v5 = (u >= 16) ? wgt : 0.f;
    v0 = row_sum16(v0); v1 = row_sum16(v1); v2 = row_sum16(v2);
    v3 = row_sum16(v3); v4 = row_sum16(v4); v5 = row_sum16(v5);
    v0 += __shfl_xor(v0, 16); v1 += __shfl_xor(v1, 16);
    v2 += __shfl_xor(v2, 16); v3 += __shfl_xor(v3, 16);
    v4 += __shfl_xor(v4, 16); v5 += __shfl_xor(v5, 16);
    if (u == 0) {
        red[g * 6 + 0] = v0; red[g * 6 + 1] = v1; red[g * 6 + 2] = v2;
        red[g * 6 + 3] = v3; red[g * 6 + 4] = v4; red[g * 6 + 5] = v5;
    }
    __syncthreads();
    if (t < 48) {
        int g2 = t / 6, s = t - g2 * 6;
        int row = ((s & 1) ? 24 : 0) + (s >> 1) * 8 + g2;
        P[(size_t)row * 1024 + b] = red[g2 * 6 + s];
    }
}

// =============== K5: fused QK/BN/exp2 -> dual-channel PV, Pm in bf16,
//                 DPP stats, shift-free softmax ===============
__global__ __launch_bounds__(256) void k_main8(float* __restrict__ qkv,
                                               const float* __restrict__ rel,
                                               const float* __restrict__ tabrv,
                                               const float* __restrict__ prmQ,
                                               const float* __restrict__ prmS,
                                               float* __restrict__ P2,
                                               int useP2) {
    const int bg = blockIdx.x;
    const int g = bg & 7;
    __shared__ __align__(16) float S[16 * 60];       // q 0-3, k 4-7, v 8-15
    __shared__ __align__(16) float rall[1776];       // rq[4][111] rk[4][111] rvrev[8][111]
    __shared__ __align__(16) unsigned short Pms[56 * 72];  // bf16 exp values
    __shared__ float red[128];

    const int t = threadIdx.x;
    float* span = qkv + (size_t)bg * 896;

    if (t < 224) {
        int e0 = t * 4;
        int c = e0 / 56, i = e0 - c * 56;
        int ch = g * 16 + c;
        float sc = prmQ[ch], sh = prmQ[128 + ch];
        float4 vv = *(const float4*)&span[e0];
        float4 o;
        o.x = vv.x * sc + sh; o.y = vv.y * sc + sh;
        o.z = vv.z * sc + sh; o.w = vv.w * sc + sh;
        *(float4*)&S[c * 60 + i] = o;
    }
    for (int idx = t; idx < 222; idx += 256)
        *(float4*)&rall[idx * 4] = *(const float4*)&rel[idx * 4];
    for (int idx = t; idx < 222; idx += 256)
        *(float4*)&rall[888 + idx * 4] = *(const float4*)&tabrv[idx * 4];
    __syncthreads();

    const int lane = t & 63, w = t >> 6;
    const int i_base = w * 14;
    const bool act = lane < 56;
    const int j = act ? lane : 0;

    const float k0 = S[240 + j], k1 = S[300 + j], k2 = S[360 + j], k3 = S[420 + j];
    const float LOG2E = 1.4426950408889634f;
    const float sc_qk = prmS[g] * LOG2E, sc_qr = prmS[8 + g] * LOG2E, sc_kr = prmS[16 + g] * LOG2E;

#pragma unroll 2
    for (int r = 0; r < 14; r += 2) {
        const int i0 = i_base + r;
        f32x2 q0 = *(const f32x2*)&S[i0];
        f32x2 q1 = *(const f32x2*)&S[60 + i0];
        f32x2 q2 = *(const f32x2*)&S[120 + i0];
        f32x2 q3 = *(const f32x2*)&S[180 + i0];
        const float* rq = &rall[i0 - j + 55];
        const float* rk = &rall[444 + j - i0 + 54];

        f32x2 qk = q0 * k0;
        qk = fma2(q1, sp2(k1), qk);
        qk = fma2(q2, sp2(k2), qk);
        qk = fma2(q3, sp2(k3), qk);

        f32x2 rq0 = {rq[0], rq[1]},     rq1 = {rq[111], rq[112]};
        f32x2 rq2 = {rq[222], rq[223]}, rq3 = {rq[333], rq[334]};
        f32x2 qr = q0 * rq0;
        qr = fma2(q1, rq1, qr);
        qr = fma2(q2, rq2, qr);
        qr = fma2(q3, rq3, qr);

        f32x2 rk0 = {rk[1], rk[0]},     rk1 = {rk[112], rk[111]};
        f32x2 rk2 = {rk[223], rk[222]}, rk3 = {rk[334], rk[333]};
        f32x2 kr = sp2(k0) * rk0;
        kr = fma2(sp2(k1), rk1, kr);
        kr = fma2(sp2(k2), rk2, kr);
        kr = fma2(sp2(k3), rk3, kr);

        f32x2 s = qk * sc_qk;
        s = fma2(qr, sp2(sc_qr), s);
        s = fma2(kr, sp2(sc_kr), s);
        float e0 = __builtin_amdgcn_exp2f(s.x);
        float e1 = __builtin_amdgcn_exp2f(s.y);
        if (act) {
            unsigned int b0 = __float_as_uint(e0);
            unsigned int b1 = __float_as_uint(e1);
            Pms[i0 * 72 + j] = (unsigned short)((b0 + 0x8000u) >> 16);
            Pms[(i0 + 1) * 72 + j] = (unsigned short)((b1 + 0x8000u) >> 16);
        }
    }
    // no __syncthreads: each wave consumes only its own rows (DS pipe in-order)

    const int il = lane & 15, cc = lane >> 4;
    const bool pact = il < 14;
    const int i = pact ? (i_base + il) : i_base;
    const int cA = cc, cB = cc + 4;

    const unsigned short* Pb = &Pms[i * 72];
    const float* vbA = &S[(8 + cA) * 60];
    const float* vbB = &S[(8 + cB) * 60];
    const float* rvA = &rall[888 + cA * 111 + 55 - i];
    const float* rvB = &rall[888 + cB * 111 + 55 - i];
    f32x4 svA = {0, 0, 0, 0}, sveA = {0, 0, 0, 0};
    f32x4 svB = {0, 0, 0, 0}, sveB = {0, 0, 0, 0};
    f32x4 rs4 = {0, 0, 0, 0};
    for (int jj = 0; jj < 56; jj += 8) {
        uint4 pu = *(const uint4*)&Pb[jj];
        f32x4 pa = {__uint_as_float(pu.x << 16), __uint_as_float(pu.x & 0xFFFF0000u),
                    __uint_as_float(pu.y << 16), __uint_as_float(pu.y & 0xFFFF0000u)};
        f32x4 pb = {__uint_as_float(pu.z << 16), __uint_as_float(pu.z & 0xFFFF0000u),
                    __uint_as_float(pu.w << 16), __uint_as_float(pu.w & 0xFFFF0000u)};
        f32x4 vA0 = *(const f32x4*)&vbA[jj],   vA1 = *(const f32x4*)&vbA[jj + 4];
        f32x4 vB0 = *(const f32x4*)&vbB[jj],   vB1 = *(const f32x4*)&vbB[jj + 4];
        f32x4 rA0 = {rvA[jj], rvA[jj + 1], rvA[jj + 2], rvA[jj + 3]};
        f32x4 rA1 = {rvA[jj + 4], rvA[jj + 5], rvA[jj + 6], rvA[jj + 7]};
        f32x4 rB0 = {rvB[jj], rvB[jj + 1], rvB[jj + 2], rvB[jj + 3]};
        f32x4 rB1 = {rvB[jj + 4], rvB[jj + 5], rvB[jj + 6], rvB[jj + 7]};
        svA = fma4(pa, vA0, svA);   svA = fma4(pb, vA1, svA);
        sveA = fma4(pa, rA0, sveA); sveA = fma4(pb, rA1, sveA);
        svB = fma4(pa, vB0, svB);   svB = fma4(pb, vB1, svB);
        sveB = fma4(pa, rB0, sveB); sveB = fma4(pb, rB1, sveB);
        rs4 += pa; rs4 += pb;
    }
    float rs = (rs4.x + rs4.y) + (rs4.z + rs4.w);
    float inv = __builtin_amdgcn_rcpf(rs);
    float sva = ((svA.x + svA.y) + (svA.z + svA.w)) * inv;
    float svea = ((sveA.x + sveA.y) + (sveA.z + sveA.w)) * inv;
    float svb = ((svB.x + svB.y) + (svB.z + svB.w)) * inv;
    float sveb = ((sveB.x + sveB.y) + (sveB.z + sveB.w)) * inv;
    if (pact) {
        span[(cA * 2) * 56 + i] = sva;
        span[(cA * 2 + 1) * 56 + i] = svea;
        span[(cB * 2) * 56 + i] = svb;
        span[(cB * 2 + 1) * 56 + i] = sveb;
    }
    float a0 = pact ? sva : 0.f,  a1 = pact ? sva * sva : 0.f;
    float a2 = pact ? svea : 0.f, a3 = pact ? svea * svea : 0.f;
    float a4 = pact ? svb : 0.f,  a5 = pact ? svb * svb : 0.f;
    float a6 = pact ? sveb : 0.f, a7 = pact ? sveb * sveb : 0.f;
    a0 = row_sum16(a0); a1 = row_sum16(a1); a2 = row_sum16(a2); a3 = row_sum16(a3);
    a4 = row_sum16(a4); a5 = row_sum16(a5); a6 = row_sum16(a6); a7 = row_sum16(a7);
    if (il == 0) {
        int baseA = cc * 16 + w;
        int baseB = (4 + cc) * 16 + w;
        red[baseA + 0]  = a0;  red[baseA + 4]  = a1;
        red[baseA + 8]  = a2;  red[baseA + 12] = a3;
        red[baseB + 0]  = a4;  red[baseB + 4]  = a5;
        red[baseB + 8]  = a6;  red[baseB + 12] = a7;
    }
    __syncthreads();
    if (useP2 && t < 32) {
        float s = red[t * 4] + red[t * 4 + 1] + red[t * 4 + 2] + red[t * 4 + 3];
        int pass = t >> 4, cc2 = (t >> 2) & 3, v = t & 3;
        int c = cc2 + (pass << 2);
        int ch = g * 16 + c * 2 + (v >> 1);
        int row = (v & 1) ? (128 + ch) : ch;
        P2[(size_t)row * 1024 + (bg >> 3)] = s;
    }
}

// =============== fallback out stats ===============
__global__ __launch_bounds__(256) void k_stats(const float* __restrict__ so,
                                               float* __restrict__ sums) {
    const int t = threadIdx.x;
    const int o = blockIdx.x >> 3;
    const int b0 = (blockIdx.x & 7) << 7;
    float s1 = 0.f, s2 = 0.f;
#pragma unroll
    for (int j = 0; j < 7; ++j) {
        int f = (j << 8) + t;
        int row = f / 14, q = f - row * 14;
        const float* src = so + ((size_t)(b0 + row) * 128 + o) * 56 + (q << 2);
        float4 v = *(const float4*)src;
        s1 += v.x + v.y + v.z + v.w;
        s2 += v.x * v.x + v.y * v.y + v.z * v.z + v.w * v.w;
    }
#pragma unroll
    for (int off = 32; off > 0; off >>= 1) { s1 += __shfl_xor(s1, off); s2 += __shfl_xor(s2, off); }
    if ((t & 63) == 0) { atomicAdd(&sums[o], s1); atomicAdd(&sums[128 + o], s2); }
}

// =============== K7: out BN (per-block derived from P2, no fence needed —
//                 P2 produced by previous dispatch) + pair-sum + transpose ===============
__global__ __launch_bounds__(256) void k_out3(const float* __restrict__ so,
                                              const float* __restrict__ P2,
                                              const float* __restrict__ prmO,
                                              const float* __restrict__ gO,
                                              const float* __restrict__ bO,
                                              float* __restrict__ out,
                                              int useP2) {
    __shared__ float L[128 * 61];
    __shared__ float rsum[8];
    __shared__ float pr[8];                    // sc[4], sh[4] for channels o0..o0+3
    const int t = threadIdx.x;
    const int s = blockIdx.x & 31;
    const int pc = blockIdx.x >> 5;
    const int o0 = pc << 2;
    const int p0 = pc << 1;

    if (useP2) {
        int rr = t >> 5, l32 = t & 31;         // 8 rows x 32 threads
        int ch = o0 + (rr & 3);
        int prow = (rr < 4) ? ch : (128 + ch);
        const float* rp = P2 + (size_t)prow * 1024 + l32 * 32;
        f32x4 a4 = {0, 0, 0, 0};
#pragma unroll
        for (int p = 0; p < 8; ++p) a4 += *(const f32x4*)&rp[p * 4];
        float sv = (a4.x + a4.y) + (a4.z + a4.w);
        sv = row_sum16(sv);
        sv += __shfl_xor(sv, 16);
        if (l32 == 0) rsum[rr] = sv;
        __syncthreads();
        if (t < 4) {
            float m = rsum[t] * (1.f / 57344.f);
            float v = rsum[4 + t] * (1.f / 57344.f) - m * m;
            float sc = gO[o0 + t] * rsqrtf(v + EPS);
            pr[t] = sc;
            pr[4 + t] = bO[o0 + t] - m * sc;
        }
    } else {
        if (t < 4) {
            pr[t] = prmO[o0 + t];
            pr[4 + t] = prmO[128 + o0 + t];
        }
    }
    __syncthreads();

#pragma unroll
    for (int j = 0; j < 7; ++j) {
        int f = (j << 8) + t;
        int row = f / 14, q = f - row * 14;
        int ch = row >> 5, wcol = row & 31;
        const float* src = so + ((size_t)(s * 32 + wcol) * 128 + o0 + ch) * 56 + (q << 2);
        float4 v = *(const float4*)src;
        float* dst = &L[row * 61 + (q << 2)];
        dst[0] = v.x; dst[1] = v.y; dst[2] = v.z; dst[3] = v.w;
    }
    __syncthreads();
#pragma unroll
    for (int j = 0; j < 14; ++j) {
        int flat = (j << 8) + t;
        int wcol = flat & 31, r = flat >> 5;
        int i = r % 56, pp = r / 56;
        float v0 = L[((pp * 2) * 32 + wcol) * 61 + i];
        float v1 = L[((pp * 2 + 1) * 32 + wcol) * 61 + i];
        float sc0 = pr[(pp << 1)],     sh0 = pr[4 + (pp << 1)];
        float sc1 = pr[(pp << 1) + 1], sh1 = pr[4 + (pp << 1) + 1];
        out[(((size_t)(p0 + pp) * 32 + s) * 56 + i) * 32 + wcol] =
            v0 * sc0 + sh0 + v1 * sc1 + sh1;
    }
}

extern "C" void kernel_launch(void* const* d_in, const int* in_sizes, int n_in,
                              void* d_out, int out_size, void* d_ws, size_t ws_size,
                              hipStream_t stream) {
    const float* x     = (const float*)d_in[0];
    const float* w_qkv = (const float*)d_in[1];
    const float* g_qkv = (const float*)d_in[2];
    const float* b_qkv = (const float*)d_in[3];
    const float* g_sim = (const float*)d_in[4];
    const float* b_sim = (const float*)d_in[5];
    const float* g_out = (const float*)d_in[6];
    const float* b_out = (const float*)d_in[7];
    const float* rel   = (const float*)d_in[8];
    float* out = (float*)d_out;

    float* ws    = (float*)d_ws;
    float* qkv   = ws;
    float* Pq    = ws + 7340032;
    float* prm   = ws + 7397376;
    float* tab   = ws + 7397936;
    float* sumsO = ws + 7401064;
    float* P2    = ws + 7401472;
    const bool big = ws_size >= (size_t)(7401472 + 262144) * sizeof(float);

    k_qkv2<<<449, 256, 0, stream>>>(x, w_qkv, rel, qkv, Pq, tab);
    k_fin_red<<<128, 256, 0, stream>>>(Pq, g_qkv, b_qkv, prm, 128, 224, 1.f / 57344.f);
    k_sim3<<<1024, 256, 0, stream>>>(qkv, prm, tab, Pq);
    k_fin_red<<<24, 256, 0, stream>>>(Pq, g_sim, b_sim, prm + 256, 24, 1024, 1.f / 3211264.f);

    if (big) {
        k_main8<<<8192, 256, 0, stream>>>(qkv, rel, tab + 2240, prm, prm + 256, P2, 1);
        k_out3<<<1024, 256, 0, stream>>>(qkv, P2, prm + 304, g_out, b_out, out, 1);
    } else {
        hipMemsetAsync(sumsO, 0, 256 * sizeof(float), stream);
        k_main8<<<8192, 256, 0, stream>>>(qkv, rel, tab + 2240, prm, prm + 256, sumsO, 0);
        k_stats<<<1024, 256, 0, stream>>>(qkv, sumsO);
        k_fin<<<1, 128, 0, stream>>>(sumsO, g_out, b_out, prm + 304, 128, 1.f / 57344.f);
        k_out3<<<1024, 256, 0, stream>>>(qkv, P2, prm + 304, g_out, b_out, out, 0);
    }
}